// Round 1
// baseline (616.921 us; speedup 1.0000x reference)
//
#include <hip/hip_runtime.h>
#include <math.h>

namespace {
constexpr int B_ = 16, C_ = 512, H_ = 28, W_ = 28, O_ = 1024;
constexpr int Ho_ = 14, Wo_ = 14, G_ = 4;
constexpr int N_ = B_ * Ho_ * Wo_;   // 3136
constexpr int HW_ = Ho_ * Wo_;       // 196

// ws layout (bytes):
//   [0..3]   a_max bits (u32), [4..7] w_max bits (u32)
//   [64..]   ch_scale: 512 floats (inv_rsqrt * gamma per channel)
//   [4096..] act bit-planes: u32[N_*G_*8*4]  (index ((n*4+g)*8+z)*4+w32)
//   [WGT..]  wgt bit-planes: u32[O_*G_*8*4]  (index ((o*4+g)*8+j)*4+w32)
constexpr size_t SCALE_OFF_B = 64;
constexpr size_t ACT_OFF_B   = 4096;
constexpr size_t ACT_WORDS   = (size_t)N_ * G_ * 8 * 4;     // 401408
constexpr size_t WGT_OFF_B   = ACT_OFF_B + ACT_WORDS * 4;   // 1609728 (16B aligned)
}

// q = floor((63*P + 640)/1280) == round-half-even(63*P/1280) for all P in [0,1280]
// (only exact-half case P=640 -> 31.5 -> 32 under both rules).
__device__ __forceinline__ unsigned rq1280(unsigned t /* = 63*P + 640, t <= 81280 */) {
  return __umul24(t >> 8, 205u) >> 10;   // floor(floor(t/256)/5) == floor(t/1280)
}

__global__ void init_ws_kernel(unsigned* ws) {
  if (threadIdx.x < 2) ws[threadIdx.x] = 0u;
}

__global__ void prep_scale_kernel(const float* __restrict__ gamma,
                                  const float* __restrict__ var,
                                  float* __restrict__ chs) {
#pragma clang fp contract(off)
  int c = blockIdx.x * blockDim.x + threadIdx.x;
  if (c < C_) {
    float vf = var[c] + 1e-5f;
    float inv = (float)(1.0 / sqrt((double)vf));   // correctly-rounded f32 rsqrt emulation
    chs[c] = inv * gamma[c];
  }
}

__global__ void amax_kernel(const float* __restrict__ x,
                            const float* __restrict__ mean,
                            const float* __restrict__ beta,
                            const float* __restrict__ chs,
                            unsigned* __restrict__ ws) {
#pragma clang fp contract(off)
  float m = 0.f;
  const int total = B_ * C_ * H_ * W_;
  for (int i = blockIdx.x * blockDim.x + threadIdx.x; i < total;
       i += gridDim.x * blockDim.x) {
    int c = (i / (H_ * W_)) % C_;
    float xh = (x[i] - mean[c]) * chs[c] + beta[c];
    xh = fmaxf(xh, 0.f);
    m = fmaxf(m, xh);
  }
#pragma unroll
  for (int off = 32; off > 0; off >>= 1)
    m = fmaxf(m, __shfl_down(m, off, 64));
  if ((threadIdx.x & 63) == 0) atomicMax(ws + 0, __float_as_uint(m));
}

__global__ void wmax_kernel(const float* __restrict__ w, unsigned* __restrict__ ws) {
  int i = blockIdx.x * blockDim.x + threadIdx.x;   // exactly O_*C_ threads
  float m = fabsf(w[i]);
#pragma unroll
  for (int off = 32; off > 0; off >>= 1)
    m = fmaxf(m, __shfl_down(m, off, 64));
  if ((threadIdx.x & 63) == 0) atomicMax(ws + 1, __float_as_uint(m));
}

// one thread per (n, g, w32): packs 32 channels into 8 bit-plane words
__global__ void pack_x_kernel(const float* __restrict__ x,
                              const float* __restrict__ mean,
                              const float* __restrict__ beta,
                              const float* __restrict__ chs,
                              const unsigned* __restrict__ ws,
                              unsigned* __restrict__ act) {
#pragma clang fp contract(off)
  int t = blockIdx.x * blockDim.x + threadIdx.x;   // 50176 total
  int w32 = t & 3;
  int g = (t >> 2) & 3;
  int n = t >> 4;
  int b = n / HW_;
  int hw = n - b * HW_;
  int h2 = (hw / Wo_) * 2;
  int w2 = (hw % Wo_) * 2;
  float amax = fmaxf(__uint_as_float(ws[0]), 1e-8f);
  unsigned bits[8] = {0, 0, 0, 0, 0, 0, 0, 0};
  int cbase = g * 128 + w32 * 32;
#pragma unroll 4
  for (int j = 0; j < 32; ++j) {
    int c = cbase + j;
    float xv = x[((size_t)(b * C_ + c) * H_ + h2) * W_ + w2];
    float xh = (xv - mean[c]) * chs[c] + beta[c];
    xh = fmaxf(xh, 0.f);
    float u = xh / amax;
    u = fminf(fmaxf(u, 0.f), 1.f);
    int xi = (int)rintf(u * 255.0f);   // half-even, matches jnp.round
#pragma unroll
    for (int z = 0; z < 8; ++z) bits[z] |= (unsigned)((xi >> z) & 1) << j;
  }
#pragma unroll
  for (int z = 0; z < 8; ++z)
    act[((size_t)(n * 4 + g) * 8 + z) * 4 + w32] = bits[z];
}

// one thread per (o, g, w32)
__global__ void pack_w_kernel(const float* __restrict__ w,
                              const unsigned* __restrict__ ws,
                              unsigned* __restrict__ wgt) {
#pragma clang fp contract(off)
  int t = blockIdx.x * blockDim.x + threadIdx.x;   // 16384 total
  int w32 = t & 3;
  int g = (t >> 2) & 3;
  int o = t >> 4;
  float wmax = fmaxf(__uint_as_float(ws[1]), 1e-8f);
  unsigned bits[8] = {0, 0, 0, 0, 0, 0, 0, 0};
  int cbase = g * 128 + w32 * 32;
#pragma unroll 4
  for (int j = 0; j < 32; ++j) {
    float v = w[(size_t)o * C_ + cbase + j] / wmax;
    v = fminf(fmaxf(v, -1.f), 1.f);
    int wi = (int)rintf(v * 127.0f);
    unsigned wu = (unsigned)(wi + 128);   // [1,255]
#pragma unroll
    for (int jb = 0; jb < 8; ++jb) bits[jb] |= ((wu >> jb) & 1u) << j;
  }
#pragma unroll
  for (int jb = 0; jb < 8; ++jb)
    wgt[((size_t)(o * 4 + g) * 8 + jb) * 4 + w32] = bits[jb];
}

// block: 256 threads = 256 consecutive o; each thread does an 8-wide n tile.
__global__ __launch_bounds__(256) void shortcutq_main_kernel(
    const unsigned* __restrict__ act, const unsigned* __restrict__ wgt,
    const float* __restrict__ y, const unsigned* __restrict__ ws,
    float* __restrict__ out) {
  __shared__ uint4 sact[256];   // [n_l(8)][g(4)][z(8)]
  int o = (blockIdx.x & 3) * 256 + threadIdx.x;
  int n0 = (blockIdx.x >> 2) * 8;

  sact[threadIdx.x] = ((const uint4*)act)[(size_t)n0 * 32 + threadIdx.x];
  __syncthreads();

  int acc[8];
#pragma unroll
  for (int n = 0; n < 8; ++n) acc[n] = 0;

  for (int g = 0; g < 4; ++g) {
    uint4 wj[8];
    const uint4* wp = ((const uint4*)wgt) + (size_t)(o * 4 + g) * 8;
#pragma unroll
    for (int j = 0; j < 8; ++j) wj[j] = wp[j];

    for (int z = 0; z < 8; ++z) {
#pragma unroll
      for (int n = 0; n < 8; ++n) {
        uint4 a = sact[n * 32 + g * 8 + z];
        int xsum = __popc(a.x) + __popc(a.y) + __popc(a.z) + __popc(a.w);
        int bdp[8];
#pragma unroll
        for (int j = 0; j < 8; ++j) {
          bdp[j] = __popc(a.x & wj[j].x) + __popc(a.y & wj[j].y) +
                   __popc(a.z & wj[j].z) + __popc(a.w & wj[j].w);
        }
#pragma unroll
        for (int k = 0; k < 4; ++k) {
          int P = 3 * ((bdp[2 * k + 1] << 1) + bdp[2 * k]) + xsum;  // <= 1280
          unsigned q = rq1280(__umul24((unsigned)P, 63u) + 640u);   // <= 63
          acc[n] += (int)(q << (z + 2 * k));
        }
        // dummy column: k=0,1,2 share q0 (weights 1+4+16=21), k=3 uses 441*xsum (weight 64)
        unsigned q0 = rq1280(__umul24((unsigned)xsum, 63u) + 640u);
        unsigned q3 = rq1280(__umul24((unsigned)xsum, 441u) + 640u);
        acc[n] -= (int)((__umul24(q0, 21u) + (q3 << 6)) << z);
      }
    }
  }

  float amax = fmaxf(__uint_as_float(ws[0]), 1e-8f);
  float wmax = fmaxf(__uint_as_float(ws[1]), 1e-8f);
  const float delta = (float)((128.0 * (3.0 + 1.0 / 3.0)) / 63.0);
  float scale = delta * (wmax / 127.0f) * (amax / 255.0f);
#pragma unroll
  for (int n = 0; n < 8; ++n) {
    int nn = n0 + n;
    int b = nn / HW_;
    int hw = nn - b * HW_;
    size_t idx = ((size_t)(b * O_ + o)) * HW_ + hw;
    out[idx] = (float)acc[n] * scale + y[idx];
  }
}

extern "C" void kernel_launch(void* const* d_in, const int* in_sizes, int n_in,
                              void* d_out, int out_size, void* d_ws, size_t ws_size,
                              hipStream_t stream) {
  const float* x      = (const float*)d_in[0];
  const float* y      = (const float*)d_in[1];
  const float* gamma  = (const float*)d_in[2];
  const float* beta   = (const float*)d_in[3];
  const float* mean   = (const float*)d_in[4];
  const float* var    = (const float*)d_in[5];
  const float* w      = (const float*)d_in[6];
  float* out = (float*)d_out;

  unsigned* ws_u  = (unsigned*)d_ws;
  float*    chs   = (float*)((char*)d_ws + SCALE_OFF_B);
  unsigned* actb  = (unsigned*)((char*)d_ws + ACT_OFF_B);
  unsigned* wgtb  = (unsigned*)((char*)d_ws + WGT_OFF_B);

  hipLaunchKernelGGL(init_ws_kernel, dim3(1), dim3(64), 0, stream, ws_u);
  hipLaunchKernelGGL(prep_scale_kernel, dim3(2), dim3(256), 0, stream, gamma, var, chs);
  hipLaunchKernelGGL(amax_kernel, dim3(2048), dim3(256), 0, stream,
                     x, mean, beta, chs, ws_u);
  hipLaunchKernelGGL(wmax_kernel, dim3((O_ * C_) / 256), dim3(256), 0, stream, w, ws_u);
  hipLaunchKernelGGL(pack_x_kernel, dim3((N_ * G_ * 4) / 256), dim3(256), 0, stream,
                     x, mean, beta, chs, ws_u, actb);
  hipLaunchKernelGGL(pack_w_kernel, dim3((O_ * G_ * 4) / 256), dim3(256), 0, stream,
                     w, ws_u, wgtb);
  hipLaunchKernelGGL(shortcutq_main_kernel, dim3(4 * (N_ / 8)), dim3(256), 0, stream,
                     actb, wgtb, y, ws_u, out);
}

// Round 2
// 354.366 us; speedup vs baseline: 1.7409x; 1.7409x over previous
//
#include <hip/hip_runtime.h>
#include <math.h>

typedef __attribute__((ext_vector_type(4))) int i32x4;
typedef __attribute__((ext_vector_type(16))) int i32x16;

namespace {
constexpr int B_ = 16, C_ = 512, H_ = 28, W_ = 28, O_ = 1024;
constexpr int Ho_ = 14, Wo_ = 14;
constexpr int N_ = B_ * Ho_ * Wo_;   // 3136 spatial-batch positions
constexpr int HW_ = Ho_ * Wo_;       // 196
constexpr int M_ = N_ * 8;           // 25088 GEMM rows (n,z)
constexpr int KB_ = 512;             // K bytes per row (g-major: kappa = g*128+s = channel)

// ws layout
constexpr size_t CHS_OFF_B = 64;                       // float[512]
constexpr size_t DUM_OFF_B = 4096;                     // int[3136]
constexpr size_t ACT_OFF_B = 32768;                    // i8 [M_][512]   (12.85 MB)
constexpr size_t WGT_OFF_B = ACT_OFF_B + (size_t)M_ * KB_;  // i8 [4096][512] (2 MB)
}

// q = floor((63*P+640)/1280) == jnp.round(63P/1280) for P in [0,1280]
__device__ __forceinline__ unsigned rq1280(unsigned t) {
  return __umul24(t >> 8, 205u) >> 10;
}

__global__ void init_ws_kernel(unsigned* ws) {
  if (threadIdx.x < 2) ws[threadIdx.x] = 0u;
}

__global__ void prep_scale_kernel(const float* __restrict__ gamma,
                                  const float* __restrict__ var,
                                  float* __restrict__ chs) {
#pragma clang fp contract(off)
  int c = blockIdx.x * blockDim.x + threadIdx.x;
  if (c < C_) {
    float vf = var[c] + 1e-5f;
    float inv = (float)(1.0 / sqrt((double)vf));
    chs[c] = inv * gamma[c];
  }
}

__global__ void amax_kernel(const float* __restrict__ x,
                            const float* __restrict__ mean,
                            const float* __restrict__ beta,
                            const float* __restrict__ chs,
                            unsigned* __restrict__ ws) {
#pragma clang fp contract(off)
  __shared__ float red[4];
  float m = 0.f;
  const int total = B_ * C_ * H_ * W_;
  for (int i = blockIdx.x * blockDim.x + threadIdx.x; i < total;
       i += gridDim.x * blockDim.x) {
    int c = (i / (H_ * W_)) % C_;
    float xh = (x[i] - mean[c]) * chs[c] + beta[c];
    m = fmaxf(m, fmaxf(xh, 0.f));
  }
#pragma unroll
  for (int off = 32; off > 0; off >>= 1)
    m = fmaxf(m, __shfl_down(m, off, 64));
  if ((threadIdx.x & 63) == 0) red[threadIdx.x >> 6] = m;
  __syncthreads();
  if (threadIdx.x == 0) {
    m = fmaxf(fmaxf(red[0], red[1]), fmaxf(red[2], red[3]));
    atomicMax(ws + 0, __float_as_uint(m));
  }
}

__global__ void wmax_kernel(const float* __restrict__ w, unsigned* __restrict__ ws) {
  __shared__ float red[4];
  float m = 0.f;
  const int total = O_ * C_;
  for (int i = blockIdx.x * blockDim.x + threadIdx.x; i < total;
       i += gridDim.x * blockDim.x)
    m = fmaxf(m, fabsf(w[i]));
#pragma unroll
  for (int off = 32; off > 0; off >>= 1)
    m = fmaxf(m, __shfl_down(m, off, 64));
  if ((threadIdx.x & 63) == 0) red[threadIdx.x >> 6] = m;
  __syncthreads();
  if (threadIdx.x == 0) {
    m = fmaxf(fmaxf(red[0], red[1]), fmaxf(red[2], red[3]));
    atomicMax(ws + 1, __float_as_uint(m));
  }
}

// thread per (n, cq): 4 channels -> one u32 byte-word per z plane
__global__ void pack_x_kernel(const float* __restrict__ x,
                              const float* __restrict__ mean,
                              const float* __restrict__ beta,
                              const float* __restrict__ chs,
                              const unsigned* __restrict__ ws,
                              unsigned* __restrict__ act) {
#pragma clang fp contract(off)
  int t = blockIdx.x * blockDim.x + threadIdx.x;  // N_*128
  int cq = t & 127;
  int n = t >> 7;
  int b = n / HW_;
  int hw = n - b * HW_;
  int h2 = (hw / Wo_) * 2;
  int w2 = (hw % Wo_) * 2;
  float amax = fmaxf(__uint_as_float(ws[0]), 1e-8f);
  int xi[4];
#pragma unroll
  for (int j = 0; j < 4; ++j) {
    int c = cq * 4 + j;
    float xv = x[((size_t)(b * C_ + c) * H_ + h2) * W_ + w2];
    float xh = (xv - mean[c]) * chs[c] + beta[c];
    xh = fmaxf(xh, 0.f);
    float u = fminf(fmaxf(xh / amax, 0.f), 1.f);
    xi[j] = (int)rintf(u * 255.0f);
  }
#pragma unroll
  for (int z = 0; z < 8; ++z) {
    unsigned word = ((unsigned)((xi[0] >> z) & 1)) |
                    ((unsigned)((xi[1] >> z) & 1) << 8) |
                    ((unsigned)((xi[2] >> z) & 1) << 16) |
                    ((unsigned)((xi[3] >> z) & 1) << 24);
    act[(size_t)(n * 8 + z) * 128 + cq] = word;
  }
}

// thread per (o, k, c16): 16 channels -> 16 bytes (3*cell+1)
__global__ void pack_w_kernel(const float* __restrict__ w,
                              const unsigned* __restrict__ ws,
                              unsigned* __restrict__ wgt) {
#pragma clang fp contract(off)
  int t = blockIdx.x * blockDim.x + threadIdx.x;  // 1024*4*32
  int c16 = t & 31;
  int k = (t >> 5) & 3;
  int o = t >> 7;
  float wmax = fmaxf(__uint_as_float(ws[1]), 1e-8f);
  unsigned words[4];
#pragma unroll
  for (int q = 0; q < 4; ++q) {
    unsigned wd = 0;
#pragma unroll
    for (int j = 0; j < 4; ++j) {
      int c = c16 * 16 + q * 4 + j;
      float v = fminf(fmaxf(w[(size_t)o * C_ + c] / wmax, -1.f), 1.f);
      int wi = (int)rintf(v * 127.0f);
      unsigned wu = (unsigned)(wi + 128);
      unsigned cell = (wu >> (2 * k)) & 3u;
      wd |= (3u * cell + 1u) << (8 * j);
    }
    words[q] = wd;
  }
  unsigned* dst = wgt + ((size_t)(o * 4 + k) * 512 + c16 * 16) / 4;
  *(uint4*)dst = make_uint4(words[0], words[1], words[2], words[3]);
}

// thread per n: dummy[n] = sum_{g,z} 2^z * (21*q0 + 64*q3), q from xsum
__global__ void dummy_kernel(const uint4* __restrict__ act, int* __restrict__ dummy) {
  int n = blockIdx.x * blockDim.x + threadIdx.x;
  if (n >= N_) return;
  const uint4* a = act + (size_t)n * 8 * 32;  // 512B per (n,z) row = 32 uint4
  int dsum = 0;
  for (int z = 0; z < 8; ++z) {
#pragma unroll
    for (int g = 0; g < 4; ++g) {
      int xs = 0;
#pragma unroll
      for (int tt = 0; tt < 8; ++tt) {
        uint4 v = a[z * 32 + g * 8 + tt];  // bytes are 0/1 -> popc sums them
        xs += __popc(v.x) + __popc(v.y) + __popc(v.z) + __popc(v.w);
      }
      unsigned q0 = rq1280(__umul24((unsigned)xs, 63u) + 640u);
      unsigned q3 = rq1280(__umul24((unsigned)xs, 441u) + 640u);
      dsum += (int)((__umul24(q0, 21u) + (q3 << 6)) << z);
    }
  }
  dummy[n] = dsum;
}

__device__ __forceinline__ void gload_lds16(const void* g, void* l) {
  __builtin_amdgcn_global_load_lds(
      (const __attribute__((address_space(1))) void*)g,
      (__attribute__((address_space(3))) void*)l, 16, 0, 0);
}

// grid (196, 32): block tile 128 rows x 128 cols, K=512 in 16 steps of 32
__global__ __launch_bounds__(256) void shortcutq_main_kernel(
    const char* __restrict__ act, const char* __restrict__ wgt,
    const int* __restrict__ dummy, const float* __restrict__ y,
    const unsigned* __restrict__ ws, float* __restrict__ out) {
  __shared__ __align__(16) char lds[16384];
  const int tid = threadIdx.x;
  const int mblk = blockIdx.x;   // 196
  const int cblk = blockIdx.y;   // 32
  const int lane = tid & 63, wv = tid >> 6;
  const int rp = wv >> 1, cp = wv & 1;

  // staging source addresses (thread t stages 16B of A and 16B of B per step)
  const int srt = tid >> 6, shalf = (tid >> 5) & 1, srl = tid & 31;
  const char* gA = act + (size_t)(mblk * 128 + srt * 32 + srl) * KB_ + shalf * 16;
  const char* gB = wgt + (size_t)(cblk * 128 + srt * 32 + srl) * KB_ + shalf * 16;

  i32x16 c00, c01, c10, c11;
  int acc[2][2][4];
#pragma unroll
  for (int i = 0; i < 2; ++i)
#pragma unroll
    for (int j = 0; j < 2; ++j)
#pragma unroll
      for (int cc = 0; cc < 4; ++cc) acc[i][j][cc] = 0;
#pragma unroll
  for (int e = 0; e < 16; ++e) { c00[e] = 0; c01[e] = 0; c10[e] = 0; c11[e] = 0; }

  const int shb = 4 * (lane >> 5) + 2 * (lane & 3);

  // prologue: stage step 0 into buffer 0
  gload_lds16(gA, lds + tid * 16);
  gload_lds16(gB, lds + 4096 + tid * 16);

  for (int s = 0; s < 16; ++s) {
    __syncthreads();  // drains vmcnt: step-s staging complete; prev reads done
    if (s < 15) {
      int bb = ((s + 1) & 1) * 8192;
      gload_lds16(gA + (s + 1) * 32, lds + bb + tid * 16);
      gload_lds16(gB + (s + 1) * 32, lds + bb + 4096 + tid * 16);
    }
    const int bb = (s & 1) * 8192;
    i32x4 a0 = *(const i32x4*)(lds + bb + (rp * 2 + 0) * 1024 + lane * 16);
    i32x4 a1 = *(const i32x4*)(lds + bb + (rp * 2 + 1) * 1024 + lane * 16);
    i32x4 b0 = *(const i32x4*)(lds + bb + 4096 + (cp * 2 + 0) * 1024 + lane * 16);
    i32x4 b1 = *(const i32x4*)(lds + bb + 4096 + (cp * 2 + 1) * 1024 + lane * 16);
    c00 = __builtin_amdgcn_mfma_i32_32x32x32_i8(a0, b0, c00, 0, 0, 0);
    c01 = __builtin_amdgcn_mfma_i32_32x32x32_i8(a0, b1, c01, 0, 0, 0);
    c10 = __builtin_amdgcn_mfma_i32_32x32x32_i8(a1, b0, c10, 0, 0, 0);
    c11 = __builtin_amdgcn_mfma_i32_32x32x32_i8(a1, b1, c11, 0, 0, 0);

    if ((s & 3) == 3) {  // end of one g: quantize and accumulate
#pragma unroll
      for (int cc = 0; cc < 4; ++cc) {
#pragma unroll
        for (int r = 0; r < 4; ++r) {
          unsigned t0 = __umul24((unsigned)c00[4 * cc + r], 63u) + 640u;
          acc[0][0][cc] += (int)((__umul24(t0 >> 8, 205u) >> 10) << (shb + r));
          unsigned t1 = __umul24((unsigned)c01[4 * cc + r], 63u) + 640u;
          acc[0][1][cc] += (int)((__umul24(t1 >> 8, 205u) >> 10) << (shb + r));
          unsigned t2 = __umul24((unsigned)c10[4 * cc + r], 63u) + 640u;
          acc[1][0][cc] += (int)((__umul24(t2 >> 8, 205u) >> 10) << (shb + r));
          unsigned t3 = __umul24((unsigned)c11[4 * cc + r], 63u) + 640u;
          acc[1][1][cc] += (int)((__umul24(t3 >> 8, 205u) >> 10) << (shb + r));
        }
      }
#pragma unroll
      for (int e = 0; e < 16; ++e) { c00[e] = 0; c01[e] = 0; c10[e] = 0; c11[e] = 0; }
    }
  }

  // reduction: partials -> LDS -> 8-way sum per (n,o)
  __syncthreads();
  int* r32 = (int*)lds;
  const int olane = (lane >> 2) & 7;
  const int p = ((lane >> 5) << 2) | (lane & 3);
#pragma unroll
  for (int i = 0; i < 2; ++i)
#pragma unroll
    for (int j = 0; j < 2; ++j)
#pragma unroll
      for (int cc = 0; cc < 4; ++cc) {
        int nl = rp * 8 + i * 4 + cc;
        int ol = (cp * 2 + j) * 8 + olane;
        r32[(nl * 32 + ol) * 8 + p] = acc[i][j][cc];
      }
  __syncthreads();

  float amaxv = fmaxf(__uint_as_float(ws[0]), 1e-8f);
  float wmaxv = fmaxf(__uint_as_float(ws[1]), 1e-8f);
  const float delta = (float)((128.0 * (3.0 + 1.0 / 3.0)) / 63.0);
  float scale = delta * (wmaxv / 127.0f) * (amaxv / 255.0f);

#pragma unroll
  for (int u = 0; u < 2; ++u) {
    int id = tid * 2 + u;
    int nl = id >> 5, ol = id & 31;
    const i32x4 v0 = *(const i32x4*)(r32 + id * 8);
    const i32x4 v1 = *(const i32x4*)(r32 + id * 8 + 4);
    int S = v0.x + v0.y + v0.z + v0.w + v1.x + v1.y + v1.z + v1.w;
    int n = mblk * 16 + nl;
    int o = cblk * 32 + ol;
    int b = n / HW_;
    int hw = n - b * HW_;
    size_t idx = ((size_t)(b * O_ + o)) * HW_ + hw;
    out[idx] = (float)(S - dummy[n]) * scale + y[idx];
  }
}

extern "C" void kernel_launch(void* const* d_in, const int* in_sizes, int n_in,
                              void* d_out, int out_size, void* d_ws, size_t ws_size,
                              hipStream_t stream) {
  const float* x     = (const float*)d_in[0];
  const float* y     = (const float*)d_in[1];
  const float* gamma = (const float*)d_in[2];
  const float* beta  = (const float*)d_in[3];
  const float* mean  = (const float*)d_in[4];
  const float* var   = (const float*)d_in[5];
  const float* w     = (const float*)d_in[6];
  float* out = (float*)d_out;

  unsigned* ws_u = (unsigned*)d_ws;
  float* chs     = (float*)((char*)d_ws + CHS_OFF_B);
  int* dum       = (int*)((char*)d_ws + DUM_OFF_B);
  char* actb     = (char*)d_ws + ACT_OFF_B;
  char* wgtb     = (char*)d_ws + WGT_OFF_B;

  hipLaunchKernelGGL(init_ws_kernel, dim3(1), dim3(64), 0, stream, ws_u);
  hipLaunchKernelGGL(prep_scale_kernel, dim3(2), dim3(256), 0, stream, gamma, var, chs);
  hipLaunchKernelGGL(amax_kernel, dim3(256), dim3(256), 0, stream, x, mean, beta, chs, ws_u);
  hipLaunchKernelGGL(wmax_kernel, dim3(128), dim3(256), 0, stream, w, ws_u);
  hipLaunchKernelGGL(pack_x_kernel, dim3((N_ * 128) / 256), dim3(256), 0, stream,
                     x, mean, beta, chs, ws_u, (unsigned*)actb);
  hipLaunchKernelGGL(pack_w_kernel, dim3((O_ * 4 * 32) / 256), dim3(256), 0, stream,
                     w, ws_u, (unsigned*)wgtb);
  hipLaunchKernelGGL(dummy_kernel, dim3((N_ + 255) / 256), dim3(256), 0, stream,
                     (const uint4*)actb, dum);
  hipLaunchKernelGGL(shortcutq_main_kernel, dim3(196, 32), dim3(256), 0, stream,
                     actb, wgtb, dum, y, ws_u, out);
}

// Round 3
// 265.000 us; speedup vs baseline: 2.3280x; 1.3372x over previous
//
#include <hip/hip_runtime.h>
#include <math.h>

typedef __attribute__((ext_vector_type(4))) int i32x4;
typedef __attribute__((ext_vector_type(16))) int i32x16;

namespace {
constexpr int B_ = 16, C_ = 512, H_ = 28, W_ = 28, O_ = 1024;
constexpr int Ho_ = 14, Wo_ = 14;
constexpr int N_ = 3136, HW_ = 196;
constexpr int M_ = N_ * 8;       // 25088 GEMM rows (n*8+z)
// ws layout (bytes)
constexpr size_t FIN_OFF   = 0;      // float[2]: amax, wmax (written by pack kernels)
constexpr size_t AMAXP_OFF = 256;    // float[128] partials
constexpr size_t WMAXP_OFF = 768;    // float[64] partials
constexpr size_t CHS_OFF   = 1024;   // float[512]
constexpr size_t DUM_OFF   = 4096;   // int[3136]
constexpr size_t ACT_OFF   = 32768;  // u8[25088][512]
constexpr size_t WGT_OFF   = ACT_OFF + (size_t)M_ * 512;  // u8[4096][512]
}

__device__ __forceinline__ void gload_lds16(const void* g, void* l) {
  __builtin_amdgcn_global_load_lds(
      (const __attribute__((address_space(1))) void*)g,
      (__attribute__((address_space(3))) void*)l, 16, 0, 0);
}

// ---------- k1: amax partials (endpoint trick) + wmax partials + chs ----------
__global__ __launch_bounds__(256) void prep1_kernel(
    const float* __restrict__ x, const float* __restrict__ w,
    const float* __restrict__ gamma, const float* __restrict__ beta,
    const float* __restrict__ mean, const float* __restrict__ var,
    float* __restrict__ amaxp, float* __restrict__ wmaxp, float* __restrict__ chs) {
#pragma clang fp contract(off)
  __shared__ float red[4];
  const int bx = blockIdx.x, tid = threadIdx.x;
  if (bx < 128) {           // amax over x: thread = quarter of a (b,c) row
    int id = bx * 256 + tid;            // < 32768
    int row = id >> 2;                  // b*512+c
    int c = row & 511;
    const float4* p = (const float4*)(x + (size_t)row * 784 + (size_t)(id & 3) * 196);
    float mn = 1e30f, mx = -1e30f;
    for (int i = 0; i < 49; ++i) {
      float4 v = p[i];
      mn = fminf(mn, fminf(fminf(v.x, v.y), fminf(v.z, v.w)));
      mx = fmaxf(mx, fmaxf(fmaxf(v.x, v.y), fmaxf(v.z, v.w)));
    }
    float vf = var[c] + 1e-5f;
    float sc = (float)(1.0 / sqrt((double)vf)) * gamma[c];
    float f1 = (mn - mean[c]) * sc + beta[c];
    float f2 = (mx - mean[c]) * sc + beta[c];
    float m = fmaxf(fmaxf(f1, f2), 0.f);   // relu(affine) max over set = max at endpoints
#pragma unroll
    for (int o = 32; o > 0; o >>= 1) m = fmaxf(m, __shfl_down(m, o, 64));
    if ((tid & 63) == 0) red[tid >> 6] = m;
    __syncthreads();
    if (tid == 0) amaxp[bx] = fmaxf(fmaxf(red[0], red[1]), fmaxf(red[2], red[3]));
  } else if (bx < 192) {    // wmax: 16384 threads x 8 float4 = 2MB
    int id = (bx - 128) * 256 + tid;
    const float4* p = (const float4*)w + (size_t)id * 8;
    float m = 0.f;
    for (int i = 0; i < 8; ++i) {
      float4 v = p[i];
      m = fmaxf(m, fmaxf(fmaxf(fabsf(v.x), fabsf(v.y)), fmaxf(fabsf(v.z), fabsf(v.w))));
    }
#pragma unroll
    for (int o = 32; o > 0; o >>= 1) m = fmaxf(m, __shfl_down(m, o, 64));
    if ((tid & 63) == 0) red[tid >> 6] = m;
    __syncthreads();
    if (tid == 0) wmaxp[bx - 128] = fmaxf(fmaxf(red[0], red[1]), fmaxf(red[2], red[3]));
  } else {                  // chs
    int c = (bx - 192) * 256 + tid;
    float vf = var[c] + 1e-5f;
    chs[c] = (float)(1.0 / sqrt((double)vf)) * gamma[c];
  }
}

// ---------- k2: pack_x, block = (b, h2): coalesced read + LDS transpose ----------
__global__ __launch_bounds__(256) void pack_x_kernel(
    const float* __restrict__ x, const float* __restrict__ mean,
    const float* __restrict__ beta, const float* __restrict__ chs,
    const float* __restrict__ amaxp, unsigned* __restrict__ act,
    float* __restrict__ fin) {
#pragma clang fp contract(off)
  __shared__ float samax;
  __shared__ unsigned char sx[14 * 512];
  const int bx = blockIdx.x, tid = threadIdx.x;
  const int b = bx / 14, h2 = bx - b * 14;
  if (tid < 64) {
    float m = fmaxf(amaxp[tid], amaxp[tid + 64]);
#pragma unroll
    for (int o = 32; o > 0; o >>= 1) m = fmaxf(m, __shfl_down(m, o, 64));
    if (tid == 0) {
      float a = fmaxf(m, 1e-8f);
      samax = a;
      if (bx == 0) fin[0] = a;
    }
  }
  __syncthreads();
  const float amax = samax;
  // phase 1: 3584 float4 loads covering all 512 channels of even-row h=2*h2
  for (int it = 0; it < 14; ++it) {
    int id = it * 256 + tid;
    int c = id / 7, q = id - c * 7;
    const float4 v = *(const float4*)(x + (size_t)(b * 512 + c) * 784 + (size_t)h2 * 56 + q * 4);
    float sc = chs[c], mu = mean[c], be = beta[c];
    float f0 = fmaxf((v.x - mu) * sc + be, 0.f);
    int i0 = (int)rintf(fminf(fmaxf(f0 / amax, 0.f), 1.f) * 255.0f);
    float f2 = fmaxf((v.z - mu) * sc + be, 0.f);
    int i2 = (int)rintf(fminf(fmaxf(f2 / amax, 0.f), 1.f) * 255.0f);
    sx[(2 * q) * 512 + c] = (unsigned char)i0;
    sx[(2 * q + 1) * 512 + c] = (unsigned char)i2;
  }
  __syncthreads();
  // phase 2: bit-plane extraction, coalesced stores
  const int nbase = b * 196 + h2 * 14;
  for (int it = 0; it < 7; ++it) {
    int id = it * 256 + tid;
    int cq = id & 127, w2 = id >> 7;
    unsigned v = *(const unsigned*)(sx + w2 * 512 + cq * 4);
    int n = nbase + w2;
#pragma unroll
    for (int z = 0; z < 8; ++z)
      act[(size_t)(n * 8 + z) * 128 + cq] = (v >> z) & 0x01010101u;
  }
}

// ---------- k3: pack_w (bx<512) + dummy (bx>=512) ----------
__global__ __launch_bounds__(256) void pack_wd_kernel(
    const float* __restrict__ w, const float* __restrict__ wmaxp,
    const unsigned char* __restrict__ act, unsigned* __restrict__ wgt,
    int* __restrict__ dummy, float* __restrict__ fin) {
#pragma clang fp contract(off)
  const int bx = blockIdx.x, tid = threadIdx.x;
  if (bx < 512) {
    __shared__ float swmax;
    if (tid < 64) {
      float m = wmaxp[tid];
#pragma unroll
      for (int o = 32; o > 0; o >>= 1) m = fmaxf(m, __shfl_down(m, o, 64));
      if (tid == 0) {
        float a = fmaxf(m, 1e-8f);
        swmax = a;
        if (bx == 0) fin[1] = a;
      }
    }
    __syncthreads();
    const float wmax = swmax;
    int t = bx * 256 + tid;
    int c16 = t & 31, k = (t >> 5) & 3, o = t >> 7;
    unsigned words[4];
#pragma unroll
    for (int q = 0; q < 4; ++q) {
      unsigned wd = 0;
#pragma unroll
      for (int j = 0; j < 4; ++j) {
        int c = c16 * 16 + q * 4 + j;
        float v = fminf(fmaxf(w[(size_t)o * 512 + c] / wmax, -1.f), 1.f);
        int wi = (int)rintf(v * 127.0f);
        unsigned wu = (unsigned)(wi + 128);
        unsigned cell = (wu >> (2 * k)) & 3u;
        wd |= (3u * cell + 1u) << (8 * j);
      }
      words[q] = wd;
    }
    *(uint4*)(wgt + ((size_t)(o * 4 + k) * 512 + c16 * 16) / 4) =
        make_uint4(words[0], words[1], words[2], words[3]);
  } else {
    // dummy: thread per (n,z,g), 100352 threads
    int id = (bx - 512) * 256 + tid;
    int g = id & 3, z = (id >> 2) & 7, n = id >> 5;
    const uint4* a = (const uint4*)(act + (size_t)(n * 8 + z) * 512 + g * 128);
    int xs = 0;
#pragma unroll
    for (int t8 = 0; t8 < 8; ++t8) {
      uint4 v = a[t8];
      xs += __popc(v.x) + __popc(v.y) + __popc(v.z) + __popc(v.w);
    }
    unsigned q0 = (__umul24((unsigned)xs, 51610u) + 524288u) >> 20;   // round(63xs/1280)
    unsigned q3 = (__umul24((unsigned)xs, 361268u) + 524288u) >> 20;  // round(441xs/1280)
    int term = (int)((__umul24(q0, 21u) + (q3 << 6)) << z);
#pragma unroll
    for (int msk = 1; msk <= 16; msk <<= 1) term += __shfl_xor(term, msk, 64);
    if ((tid & 31) == 0) dummy[n] = term;
  }
}

// ---------- k4: main MFMA kernel. grid (32 cblk, 196 mblk), 128x128 tile ----------
__global__ __launch_bounds__(256) void shortcutq_main_kernel(
    const char* __restrict__ act, const char* __restrict__ wgt,
    const int* __restrict__ dummy, const float* __restrict__ y,
    const float* __restrict__ fin, float* __restrict__ out) {
  __shared__ __align__(16) char lds[16384];
  const int tid = threadIdx.x;
  const int cblk = blockIdx.x;   // 32  (x-fastest: wgt slice stays hot in L2)
  const int mblk = blockIdx.y;   // 196
  const int lane = tid & 63, wv = tid >> 6;

  // staging: thread t -> (half = t>>7, row = t&127); LDS layout [half][row] (16B units)
  const char* gA = act + (size_t)(mblk * 128 + (tid & 127)) * 512 + (tid >> 7) * 16;
  const char* gB = wgt + (size_t)(cblk * 128 + (tid & 127)) * 512 + (tid >> 7) * 16;
  const int ldst = tid * 16;

  // frag read bases: A[m = wv*32 + (lane&31)][k-half = lane>>5]
  const char* rA = lds + (lane >> 5) * 2048 + (wv * 32 + (lane & 31)) * 16;
  const char* rB = lds + 4096 + (lane >> 5) * 2048 + (lane & 31) * 16;

  const int shb = 4 * (lane >> 5) + 2 * (lane & 3);
  int shr[4] = {shb, shb + 1, shb + 2, shb + 3};

  i32x16 c0, c1, c2, c3;
  int acc[4][4];
#pragma unroll
  for (int i = 0; i < 4; ++i)
#pragma unroll
    for (int j = 0; j < 4; ++j) acc[i][j] = 0;

  gload_lds16(gA, lds + ldst);
  gload_lds16(gB, lds + 4096 + ldst);

#pragma unroll
  for (int s = 0; s < 16; ++s) {
    __syncthreads();
    if (s < 15) {
      const int nb = ((s + 1) & 1) * 8192;
      gload_lds16(gA + (s + 1) * 32, lds + nb + ldst);
      gload_lds16(gB + (s + 1) * 32, lds + nb + 4096 + ldst);
    }
    const int cb = (s & 1) * 8192;
    i32x4 a = *(const i32x4*)(rA + cb);
    if ((s & 3) == 0) {
#pragma unroll
      for (int e = 0; e < 16; ++e) { c0[e] = 0; c1[e] = 0; c2[e] = 0; c3[e] = 0; }
    }
    i32x4 b0 = *(const i32x4*)(rB + cb);
    i32x4 b1 = *(const i32x4*)(rB + cb + 512);
    i32x4 b2 = *(const i32x4*)(rB + cb + 1024);
    i32x4 b3 = *(const i32x4*)(rB + cb + 1536);
    c0 = __builtin_amdgcn_mfma_i32_32x32x32_i8(a, b0, c0, 0, 0, 0);
    c1 = __builtin_amdgcn_mfma_i32_32x32x32_i8(a, b1, c1, 0, 0, 0);
    c2 = __builtin_amdgcn_mfma_i32_32x32x32_i8(a, b2, c2, 0, 0, 0);
    c3 = __builtin_amdgcn_mfma_i32_32x32x32_i8(a, b3, c3, 0, 0, 0);
    if ((s & 3) == 3) {   // end of group g: quantize (3 VALU ops/element)
#pragma unroll
      for (int e = 0; e < 16; ++e) {
        unsigned q0q = (__umul24((unsigned)c0[e], 51610u) + 524288u) >> 20;
        acc[0][e >> 2] += (int)(q0q << shr[e & 3]);
        unsigned q1q = (__umul24((unsigned)c1[e], 51610u) + 524288u) >> 20;
        acc[1][e >> 2] += (int)(q1q << shr[e & 3]);
        unsigned q2q = (__umul24((unsigned)c2[e], 51610u) + 524288u) >> 20;
        acc[2][e >> 2] += (int)(q2q << shr[e & 3]);
        unsigned q3q = (__umul24((unsigned)c3[e], 51610u) + 524288u) >> 20;
        acc[3][e >> 2] += (int)(q3q << shr[e & 3]);
      }
    }
  }

  // epilogue: sum over k (lane^1, lane^2) and z-half (lane^32)
  const float scale = (float)((128.0 * (3.0 + 1.0 / 3.0)) / 63.0) *
                      (fin[1] / 127.0f) * (fin[0] / 255.0f);
  int sums[4][4];
#pragma unroll
  for (int cp = 0; cp < 4; ++cp)
#pragma unroll
    for (int cc = 0; cc < 4; ++cc) {
      int v = acc[cp][cc];
      v += __shfl_xor(v, 1, 64);
      v += __shfl_xor(v, 2, 64);
      v += __shfl_xor(v, 32, 64);
      sums[cp][cc] = v;
    }
  if ((lane & 3) == 0 && lane < 32) {
    const int ol = lane >> 2;   // 0..7
#pragma unroll
    for (int cc = 0; cc < 4; ++cc) {
      int n = mblk * 16 + wv * 4 + cc;
      int d = dummy[n];
      int b = n / 196, hw = n - b * 196;
#pragma unroll
      for (int cp = 0; cp < 4; ++cp) {
        int o = cblk * 32 + cp * 8 + ol;
        size_t idx = ((size_t)(b * 1024 + o)) * 196 + hw;
        out[idx] = (float)(sums[cp][cc] - d) * scale + y[idx];
      }
    }
  }
}

extern "C" void kernel_launch(void* const* d_in, const int* in_sizes, int n_in,
                              void* d_out, int out_size, void* d_ws, size_t ws_size,
                              hipStream_t stream) {
  const float* x     = (const float*)d_in[0];
  const float* y     = (const float*)d_in[1];
  const float* gamma = (const float*)d_in[2];
  const float* beta  = (const float*)d_in[3];
  const float* mean  = (const float*)d_in[4];
  const float* var   = (const float*)d_in[5];
  const float* w     = (const float*)d_in[6];
  float* out = (float*)d_out;

  char* wsb = (char*)d_ws;
  float* fin    = (float*)(wsb + FIN_OFF);
  float* amaxp  = (float*)(wsb + AMAXP_OFF);
  float* wmaxp  = (float*)(wsb + WMAXP_OFF);
  float* chs    = (float*)(wsb + CHS_OFF);
  int*   dum    = (int*)(wsb + DUM_OFF);
  char*  actb   = wsb + ACT_OFF;
  char*  wgtb   = wsb + WGT_OFF;

  hipLaunchKernelGGL(prep1_kernel, dim3(194), dim3(256), 0, stream,
                     x, w, gamma, beta, mean, var, amaxp, wmaxp, chs);
  hipLaunchKernelGGL(pack_x_kernel, dim3(224), dim3(256), 0, stream,
                     x, mean, beta, chs, amaxp, (unsigned*)actb, fin);
  hipLaunchKernelGGL(pack_wd_kernel, dim3(904), dim3(256), 0, stream,
                     w, wmaxp, (const unsigned char*)actb, (unsigned*)wgtb, dum, fin);
  hipLaunchKernelGGL(shortcutq_main_kernel, dim3(32, 196), dim3(256), 0, stream,
                     actb, wgtb, dum, y, fin, out);
}

// Round 5
// 248.129 us; speedup vs baseline: 2.4863x; 1.0680x over previous
//
#include <hip/hip_runtime.h>
#include <math.h>

typedef __attribute__((ext_vector_type(4))) int i32x4;
typedef __attribute__((ext_vector_type(16))) int i32x16;

namespace {
constexpr int B_ = 16, C_ = 512, H_ = 28, W_ = 28, O_ = 1024;
constexpr int Ho_ = 14, Wo_ = 14;
constexpr int N_ = 3136, HW_ = 196;
constexpr int M_ = N_ * 8;       // 25088 GEMM rows (n*8+z)
// ws layout (bytes)
constexpr size_t FIN_OFF   = 0;      // float[2]: amax, wmax
constexpr size_t AMAXP_OFF = 256;    // float[128] partials
constexpr size_t WMAXP_OFF = 768;    // float[64] partials
constexpr size_t CHS_OFF   = 1024;   // float[512]
constexpr size_t DUM_OFF   = 4096;   // int[3136]
constexpr size_t ACT_OFF   = 32768;  // u8[25088][512]
constexpr size_t WGT_OFF   = ACT_OFF + (size_t)M_ * 512;  // u8[4096][512]
}

// offset=0 ALWAYS: the builtin's imm-offset arg is NOT applied to the global
// address for LDS-DMA on gfx950 (round-3 pass vs round-4 fail evidence).
__device__ __forceinline__ void gload(const char* g, char* l) {
  __builtin_amdgcn_global_load_lds(
      (const __attribute__((address_space(1))) char*)g,
      (__attribute__((address_space(3))) char*)l, 16, 0, 0);
}

// ---------- k1: amax partials (endpoint trick) + wmax partials + chs ----------
__global__ __launch_bounds__(256) void prep1_kernel(
    const float* __restrict__ x, const float* __restrict__ w,
    const float* __restrict__ gamma, const float* __restrict__ beta,
    const float* __restrict__ mean, const float* __restrict__ var,
    float* __restrict__ amaxp, float* __restrict__ wmaxp, float* __restrict__ chs) {
#pragma clang fp contract(off)
  __shared__ float red[4];
  const int bx = blockIdx.x, tid = threadIdx.x;
  if (bx < 128) {           // amax over x: thread = quarter of a (b,c) row
    int id = bx * 256 + tid;            // < 32768
    int row = id >> 2;                  // b*512+c
    int c = row & 511;
    const float4* p = (const float4*)(x + (size_t)row * 784 + (size_t)(id & 3) * 196);
    float mn = 1e30f, mx = -1e30f;
    for (int i = 0; i < 49; ++i) {
      float4 v = p[i];
      mn = fminf(mn, fminf(fminf(v.x, v.y), fminf(v.z, v.w)));
      mx = fmaxf(mx, fmaxf(fmaxf(v.x, v.y), fmaxf(v.z, v.w)));
    }
    float vf = var[c] + 1e-5f;
    float sc = (float)(1.0 / sqrt((double)vf)) * gamma[c];
    float f1 = (mn - mean[c]) * sc + beta[c];
    float f2 = (mx - mean[c]) * sc + beta[c];
    float m = fmaxf(fmaxf(f1, f2), 0.f);   // relu(affine) extrema at endpoints
#pragma unroll
    for (int o = 32; o > 0; o >>= 1) m = fmaxf(m, __shfl_down(m, o, 64));
    if ((tid & 63) == 0) red[tid >> 6] = m;
    __syncthreads();
    if (tid == 0) amaxp[bx] = fmaxf(fmaxf(red[0], red[1]), fmaxf(red[2], red[3]));
  } else if (bx < 192) {    // wmax
    int id = (bx - 128) * 256 + tid;
    const float4* p = (const float4*)w + (size_t)id * 8;
    float m = 0.f;
    for (int i = 0; i < 8; ++i) {
      float4 v = p[i];
      m = fmaxf(m, fmaxf(fmaxf(fabsf(v.x), fabsf(v.y)), fmaxf(fabsf(v.z), fabsf(v.w))));
    }
#pragma unroll
    for (int o = 32; o > 0; o >>= 1) m = fmaxf(m, __shfl_down(m, o, 64));
    if ((tid & 63) == 0) red[tid >> 6] = m;
    __syncthreads();
    if (tid == 0) wmaxp[bx - 128] = fmaxf(fmaxf(red[0], red[1]), fmaxf(red[2], red[3]));
  } else {                  // chs
    int c = (bx - 192) * 256 + tid;
    float vf = var[c] + 1e-5f;
    chs[c] = (float)(1.0 / sqrt((double)vf)) * gamma[c];
  }
}

// ---------- k2: pack_x ----------
__global__ __launch_bounds__(256) void pack_x_kernel(
    const float* __restrict__ x, const float* __restrict__ mean,
    const float* __restrict__ beta, const float* __restrict__ chs,
    const float* __restrict__ amaxp, unsigned* __restrict__ act,
    float* __restrict__ fin) {
#pragma clang fp contract(off)
  __shared__ float samax;
  __shared__ unsigned char sx[14 * 512];
  const int bx = blockIdx.x, tid = threadIdx.x;
  const int b = bx / 14, h2 = bx - b * 14;
  if (tid < 64) {
    float m = fmaxf(amaxp[tid], amaxp[tid + 64]);
#pragma unroll
    for (int o = 32; o > 0; o >>= 1) m = fmaxf(m, __shfl_down(m, o, 64));
    if (tid == 0) {
      float a = fmaxf(m, 1e-8f);
      samax = a;
      if (bx == 0) fin[0] = a;
    }
  }
  __syncthreads();
  const float amax = samax;
  for (int it = 0; it < 14; ++it) {
    int id = it * 256 + tid;
    int c = id / 7, q = id - c * 7;
    const float4 v = *(const float4*)(x + (size_t)(b * 512 + c) * 784 + (size_t)h2 * 56 + q * 4);
    float sc = chs[c], mu = mean[c], be = beta[c];
    float f0 = fmaxf((v.x - mu) * sc + be, 0.f);
    int i0 = (int)rintf(fminf(fmaxf(f0 / amax, 0.f), 1.f) * 255.0f);
    float f2 = fmaxf((v.z - mu) * sc + be, 0.f);
    int i2 = (int)rintf(fminf(fmaxf(f2 / amax, 0.f), 1.f) * 255.0f);
    sx[(2 * q) * 512 + c] = (unsigned char)i0;
    sx[(2 * q + 1) * 512 + c] = (unsigned char)i2;
  }
  __syncthreads();
  const int nbase = b * 196 + h2 * 14;
  for (int it = 0; it < 7; ++it) {
    int id = it * 256 + tid;
    int cq = id & 127, w2 = id >> 7;
    unsigned v = *(const unsigned*)(sx + w2 * 512 + cq * 4);
    int n = nbase + w2;
#pragma unroll
    for (int z = 0; z < 8; ++z)
      act[(size_t)(n * 8 + z) * 128 + cq] = (v >> z) & 0x01010101u;
  }
}

// ---------- k3: pack_w (bx<512) + dummy (bx>=512) ----------
__global__ __launch_bounds__(256) void pack_wd_kernel(
    const float* __restrict__ w, const float* __restrict__ wmaxp,
    const unsigned char* __restrict__ act, unsigned* __restrict__ wgt,
    int* __restrict__ dummy, float* __restrict__ fin) {
#pragma clang fp contract(off)
  const int bx = blockIdx.x, tid = threadIdx.x;
  if (bx < 512) {
    __shared__ float swmax;
    if (tid < 64) {
      float m = wmaxp[tid];
#pragma unroll
      for (int o = 32; o > 0; o >>= 1) m = fmaxf(m, __shfl_down(m, o, 64));
      if (tid == 0) {
        float a = fmaxf(m, 1e-8f);
        swmax = a;
        if (bx == 0) fin[1] = a;
      }
    }
    __syncthreads();
    const float wmax = swmax;
    int t = bx * 256 + tid;
    int c16 = t & 31, k = (t >> 5) & 3, o = t >> 7;
    unsigned words[4];
#pragma unroll
    for (int q = 0; q < 4; ++q) {
      unsigned wd = 0;
#pragma unroll
      for (int j = 0; j < 4; ++j) {
        int c = c16 * 16 + q * 4 + j;
        float v = fminf(fmaxf(w[(size_t)o * 512 + c] / wmax, -1.f), 1.f);
        int wi = (int)rintf(v * 127.0f);
        unsigned wu = (unsigned)(wi + 128);
        unsigned cell = (wu >> (2 * k)) & 3u;
        wd |= (3u * cell + 1u) << (8 * j);
      }
      words[q] = wd;
    }
    *(uint4*)(wgt + ((size_t)(o * 4 + k) * 512 + c16 * 16) / 4) =
        make_uint4(words[0], words[1], words[2], words[3]);
  } else {
    int id = (bx - 512) * 256 + tid;
    int g = id & 3, z = (id >> 2) & 7, n = id >> 5;
    const uint4* a = (const uint4*)(act + (size_t)(n * 8 + z) * 512 + g * 128);
    int xs = 0;
#pragma unroll
    for (int t8 = 0; t8 < 8; ++t8) {
      uint4 v = a[t8];
      xs += __popc(v.x) + __popc(v.y) + __popc(v.z) + __popc(v.w);
    }
    unsigned q0 = (__umul24((unsigned)xs, 51610u) + 524288u) >> 20;   // round(63xs/1280)
    unsigned q3 = (__umul24((unsigned)xs, 361268u) + 524288u) >> 20;  // round(441xs/1280)
    int term = (int)((__umul24(q0, 21u) + (q3 << 6)) << z);
#pragma unroll
    for (int msk = 1; msk <= 16; msk <<= 1) term += __shfl_xor(term, msk, 64);
    if ((tid & 31) == 0) dummy[n] = term;
  }
}

// ---------- k4: main MFMA kernel. grid (32 cblk, 196 mblk), 128x128 tile ----------
// K staged 128 (one group g) per barrier, double-buffered: 4 barriers total.
// All K offsets via pointer arithmetic, builtin offset stays 0 (see gload note).
#define STAGE(s_, p_) {                                   \
  char* la = lds + (p_) * 32768 + ldst;                   \
  char* lb = la + 16384;                                  \
  gload(gA + (s_) * 128 +  0, la);                        \
  gload(gA + (s_) * 128 + 32, la + 4096);                 \
  gload(gA + (s_) * 128 + 64, la + 8192);                 \
  gload(gA + (s_) * 128 + 96, la + 12288);                \
  gload(gB + (s_) * 128 +  0, lb);                        \
  gload(gB + (s_) * 128 + 32, lb + 4096);                 \
  gload(gB + (s_) * 128 + 64, lb + 8192);                 \
  gload(gB + (s_) * 128 + 96, lb + 12288);                \
}

#define GSTEP(pb_, j_) {                                              \
  i32x4 a  = *(const i32x4*)(rAb + (pb_) + (j_) * 4096);              \
  i32x4 b0 = *(const i32x4*)(rBb + (pb_) + (j_) * 4096);              \
  i32x4 b1 = *(const i32x4*)(rBb + (pb_) + (j_) * 4096 + 512);        \
  i32x4 b2 = *(const i32x4*)(rBb + (pb_) + (j_) * 4096 + 1024);       \
  i32x4 b3 = *(const i32x4*)(rBb + (pb_) + (j_) * 4096 + 1536);       \
  c0 = __builtin_amdgcn_mfma_i32_32x32x32_i8(a, b0, c0, 0, 0, 0);     \
  c1 = __builtin_amdgcn_mfma_i32_32x32x32_i8(a, b1, c1, 0, 0, 0);     \
  c2 = __builtin_amdgcn_mfma_i32_32x32x32_i8(a, b2, c2, 0, 0, 0);     \
  c3 = __builtin_amdgcn_mfma_i32_32x32x32_i8(a, b3, c3, 0, 0, 0);     \
}

#define COMPUTE(pb_) {                                                \
  i32x16 c0, c1, c2, c3;                                              \
  _Pragma("unroll")                                                   \
  for (int e = 0; e < 16; ++e) { c0[e] = 0; c1[e] = 0; c2[e] = 0; c3[e] = 0; } \
  GSTEP(pb_, 0) GSTEP(pb_, 1) GSTEP(pb_, 2) GSTEP(pb_, 3)             \
  _Pragma("unroll")                                                   \
  for (int e = 0; e < 16; ++e) {                                      \
    unsigned q0q = (__umul24((unsigned)c0[e], 51610u) + 524288u) >> 20; \
    acc[0][e >> 2] += (int)(q0q << shr[e & 3]);                       \
    unsigned q1q = (__umul24((unsigned)c1[e], 51610u) + 524288u) >> 20; \
    acc[1][e >> 2] += (int)(q1q << shr[e & 3]);                       \
    unsigned q2q = (__umul24((unsigned)c2[e], 51610u) + 524288u) >> 20; \
    acc[2][e >> 2] += (int)(q2q << shr[e & 3]);                       \
    unsigned q3q = (__umul24((unsigned)c3[e], 51610u) + 524288u) >> 20; \
    acc[3][e >> 2] += (int)(q3q << shr[e & 3]);                       \
  }                                                                   \
}

__global__ __launch_bounds__(256, 2) void shortcutq_main_kernel(
    const char* __restrict__ act, const char* __restrict__ wgt,
    const int* __restrict__ dummy, const float* __restrict__ y,
    const float* __restrict__ fin, float* __restrict__ out) {
  __shared__ __align__(16) char lds[65536];
  const int tid = threadIdx.x;
  const int cblk = blockIdx.x;   // 32 (x-fastest: wgt slice hot in L2)
  const int mblk = blockIdx.y;   // 196
  const int lane = tid & 63, wv = tid >> 6;

  const char* gA = act + (size_t)(mblk * 128 + (tid & 127)) * 512 + (tid >> 7) * 16;
  const char* gB = wgt + (size_t)(cblk * 128 + (tid & 127)) * 512 + (tid >> 7) * 16;
  const int ldst = tid * 16;

  const char* rAb = lds + (lane >> 5) * 2048 + (wv * 32 + (lane & 31)) * 16;
  const char* rBb = lds + 16384 + (lane >> 5) * 2048 + (lane & 31) * 16;

  const int shb = 4 * (lane >> 5) + 2 * (lane & 3);
  int shr[4] = {shb, shb + 1, shb + 2, shb + 3};

  int acc[4][4];
#pragma unroll
  for (int i = 0; i < 4; ++i)
#pragma unroll
    for (int j = 0; j < 4; ++j) acc[i][j] = 0;

  STAGE(0, 0)
  __syncthreads();
  STAGE(1, 1)
  COMPUTE(0)
  __syncthreads();
  STAGE(2, 0)
  COMPUTE(32768)
  __syncthreads();
  STAGE(3, 1)
  COMPUTE(0)
  __syncthreads();
  COMPUTE(32768)

  // epilogue: sum over k (lane^1, lane^2) and z-half (lane^32)
  const float scale = (float)((128.0 * (3.0 + 1.0 / 3.0)) / 63.0) *
                      (fin[1] / 127.0f) * (fin[0] / 255.0f);
  int sums[4][4];
#pragma unroll
  for (int cp = 0; cp < 4; ++cp)
#pragma unroll
    for (int cc = 0; cc < 4; ++cc) {
      int v = acc[cp][cc];
      v += __shfl_xor(v, 1, 64);
      v += __shfl_xor(v, 2, 64);
      v += __shfl_xor(v, 32, 64);
      sums[cp][cc] = v;
    }
  if ((lane & 3) == 0 && lane < 32) {
    const int ol = lane >> 2;   // 0..7
#pragma unroll
    for (int cc = 0; cc < 4; ++cc) {
      int n = mblk * 16 + wv * 4 + cc;
      int d = dummy[n];
      int b = n / 196, hw = n - b * 196;
#pragma unroll
      for (int cp = 0; cp < 4; ++cp) {
        int o = cblk * 32 + cp * 8 + ol;
        size_t idx = ((size_t)(b * 1024 + o)) * 196 + hw;
        out[idx] = (float)(sums[cp][cc] - d) * scale + y[idx];
      }
    }
  }
}

extern "C" void kernel_launch(void* const* d_in, const int* in_sizes, int n_in,
                              void* d_out, int out_size, void* d_ws, size_t ws_size,
                              hipStream_t stream) {
  const float* x     = (const float*)d_in[0];
  const float* y     = (const float*)d_in[1];
  const float* gamma = (const float*)d_in[2];
  const float* beta  = (const float*)d_in[3];
  const float* mean  = (const float*)d_in[4];
  const float* var   = (const float*)d_in[5];
  const float* w     = (const float*)d_in[6];
  float* out = (float*)d_out;

  char* wsb = (char*)d_ws;
  float* fin    = (float*)(wsb + FIN_OFF);
  float* amaxp  = (float*)(wsb + AMAXP_OFF);
  float* wmaxp  = (float*)(wsb + WMAXP_OFF);
  float* chs    = (float*)(wsb + CHS_OFF);
  int*   dum    = (int*)(wsb + DUM_OFF);
  char*  actb   = wsb + ACT_OFF;
  char*  wgtb   = wsb + WGT_OFF;

  hipLaunchKernelGGL(prep1_kernel, dim3(194), dim3(256), 0, stream,
                     x, w, gamma, beta, mean, var, amaxp, wmaxp, chs);
  hipLaunchKernelGGL(pack_x_kernel, dim3(224), dim3(256), 0, stream,
                     x, mean, beta, chs, amaxp, (unsigned*)actb, fin);
  hipLaunchKernelGGL(pack_wd_kernel, dim3(904), dim3(256), 0, stream,
                     w, wmaxp, (const unsigned char*)actb, (unsigned*)wgtb, dum, fin);
  hipLaunchKernelGGL(shortcutq_main_kernel, dim3(32, 196), dim3(256), 0, stream,
                     actb, wgtb, dum, y, fin, out);
}

// Round 6
// 215.105 us; speedup vs baseline: 2.8680x; 1.1535x over previous
//
#include <hip/hip_runtime.h>
#include <math.h>

typedef __attribute__((ext_vector_type(4))) int i32x4;
typedef __attribute__((ext_vector_type(16))) int i32x16;

namespace {
constexpr int B_ = 16, C_ = 512, H_ = 28, W_ = 28, O_ = 1024;
constexpr int Ho_ = 14, Wo_ = 14;
constexpr int N_ = 3136, HW_ = 196;
constexpr int M_ = N_ * 8;       // 25088 GEMM rows (n*8+z)
// ws layout (bytes)
constexpr size_t FIN_OFF   = 0;      // float[2]: amax, wmax
constexpr size_t AMAXP_OFF = 256;    // float[896] partials
constexpr size_t WMAXP_OFF = 4096;   // float[256] partials
constexpr size_t CHS_OFF   = 6144;   // float[512]
constexpr size_t DUM_OFF   = 8192;   // int[3136]
constexpr size_t ACT_OFF   = 32768;  // u8[25088][512]
constexpr size_t WGT_OFF   = ACT_OFF + (size_t)M_ * 512;  // u8[4096][512]
}

// offset=0 ALWAYS: the builtin's imm-offset arg is NOT applied to the global
// address for LDS-DMA on gfx950 (round-3 pass vs round-4 fail evidence).
__device__ __forceinline__ void gload(const char* g, char* l) {
  __builtin_amdgcn_global_load_lds(
      (const __attribute__((address_space(1))) char*)g,
      (__attribute__((address_space(3))) char*)l, 16, 0, 0);
}

// ---------- k1: amax partials (endpoint trick, 896 blk) + wmax (256 blk) + chs ----------
__global__ __launch_bounds__(256) void prep1_kernel(
    const float* __restrict__ x, const float* __restrict__ w,
    const float* __restrict__ gamma, const float* __restrict__ beta,
    const float* __restrict__ mean, const float* __restrict__ var,
    float* __restrict__ amaxp, float* __restrict__ wmaxp, float* __restrict__ chs) {
#pragma clang fp contract(off)
  __shared__ float red[4];
  const int bx = blockIdx.x, tid = threadIdx.x;
  if (bx < 896) {           // amax: thread = 28-float segment of one (b,c) row
    int id = bx * 256 + tid;            // < 229376
    int row = id / 28;                  // b*512+c
    int seg = id - row * 28;
    int c = row & 511;
    const float4* p = (const float4*)(x + (size_t)row * 784 + seg * 28);
    float mn = 1e30f, mx = -1e30f;
#pragma unroll
    for (int i = 0; i < 7; ++i) {
      float4 v = p[i];
      mn = fminf(mn, fminf(fminf(v.x, v.y), fminf(v.z, v.w)));
      mx = fmaxf(mx, fmaxf(fmaxf(v.x, v.y), fmaxf(v.z, v.w)));
    }
    float vf = var[c] + 1e-5f;
    float sc = (float)(1.0 / sqrt((double)vf)) * gamma[c];
    float f1 = (mn - mean[c]) * sc + beta[c];
    float f2 = (mx - mean[c]) * sc + beta[c];
    float m = fmaxf(fmaxf(f1, f2), 0.f);   // relu(affine) extrema at endpoints
#pragma unroll
    for (int o = 32; o > 0; o >>= 1) m = fmaxf(m, __shfl_down(m, o, 64));
    if ((tid & 63) == 0) red[tid >> 6] = m;
    __syncthreads();
    if (tid == 0) amaxp[bx] = fmaxf(fmaxf(red[0], red[1]), fmaxf(red[2], red[3]));
  } else if (bx < 1152) {   // wmax: 65536 threads x 2 float4
    int id = (bx - 896) * 256 + tid;
    const float4* p = (const float4*)w + (size_t)id * 2;
    float4 v0 = p[0], v1 = p[1];
    float m = fmaxf(fmaxf(fmaxf(fabsf(v0.x), fabsf(v0.y)), fmaxf(fabsf(v0.z), fabsf(v0.w))),
                    fmaxf(fmaxf(fabsf(v1.x), fabsf(v1.y)), fmaxf(fabsf(v1.z), fabsf(v1.w))));
#pragma unroll
    for (int o = 32; o > 0; o >>= 1) m = fmaxf(m, __shfl_down(m, o, 64));
    if ((tid & 63) == 0) red[tid >> 6] = m;
    __syncthreads();
    if (tid == 0) wmaxp[bx - 896] = fmaxf(fmaxf(red[0], red[1]), fmaxf(red[2], red[3]));
  } else {                  // chs
    int c = (bx - 1152) * 256 + tid;
    float vf = var[c] + 1e-5f;
    chs[c] = (float)(1.0 / sqrt((double)vf)) * gamma[c];
  }
}

// ---------- k2: pack_x, block = (b, h2, chalf): 448 blocks ----------
__global__ __launch_bounds__(256) void pack_x_kernel(
    const float* __restrict__ x, const float* __restrict__ mean,
    const float* __restrict__ beta, const float* __restrict__ chs,
    const float* __restrict__ amaxp, unsigned* __restrict__ act,
    float* __restrict__ fin) {
#pragma clang fp contract(off)
  __shared__ float samax;
  __shared__ unsigned char sx[14 * 256];
  const int bx = blockIdx.x, tid = threadIdx.x;
  const int chalf = bx & 1;
  const int bh = bx >> 1;
  const int b = bh / 14, h2 = bh - b * 14;
  if (tid < 64) {
    float m = 0.f;
    for (int i = tid; i < 896; i += 64) m = fmaxf(m, amaxp[i]);
#pragma unroll
    for (int o = 32; o > 0; o >>= 1) m = fmaxf(m, __shfl_down(m, o, 64));
    if (tid == 0) {
      float a = fmaxf(m, 1e-8f);
      samax = a;
      if (bx == 0) fin[0] = a;
    }
  }
  __syncthreads();
  const float amax = samax;
  const int cbase = chalf * 256;
  // phase 1: 1792 units (c_local 0..255, q 0..6) = 7 iters
  for (int it = 0; it < 7; ++it) {
    int id = it * 256 + tid;
    int cl = id / 7, q = id - cl * 7;
    int c = cbase + cl;
    const float4 v = *(const float4*)(x + (size_t)(b * 512 + c) * 784 + h2 * 56 + q * 4);
    float sc = chs[c], mu = mean[c], be = beta[c];
    float f0 = fmaxf((v.x - mu) * sc + be, 0.f);
    int i0 = (int)rintf(fminf(fmaxf(f0 / amax, 0.f), 1.f) * 255.0f);
    float f2 = fmaxf((v.z - mu) * sc + be, 0.f);
    int i2 = (int)rintf(fminf(fmaxf(f2 / amax, 0.f), 1.f) * 255.0f);
    sx[(2 * q) * 256 + cl] = (unsigned char)i0;
    sx[(2 * q + 1) * 256 + cl] = (unsigned char)i2;
  }
  __syncthreads();
  // phase 2: 896 words (w2 0..13, cq_local 0..63)
  const int nbase = b * 196 + h2 * 14;
  for (int it = 0; it < 4; ++it) {
    int id = it * 256 + tid;
    if (id < 896) {
      int cql = id & 63, w2 = id >> 6;
      unsigned v = *(const unsigned*)(sx + w2 * 256 + cql * 4);
      int n = nbase + w2;
      int cq = chalf * 64 + cql;
#pragma unroll
      for (int z = 0; z < 8; ++z)
        act[(size_t)(n * 8 + z) * 128 + cq] = (v >> z) & 0x01010101u;
    }
  }
}

// ---------- k3: pack_w (bx<512) + dummy (bx>=512) ----------
__global__ __launch_bounds__(256) void pack_wd_kernel(
    const float* __restrict__ w, const float* __restrict__ wmaxp,
    const unsigned char* __restrict__ act, unsigned* __restrict__ wgt,
    int* __restrict__ dummy, float* __restrict__ fin) {
#pragma clang fp contract(off)
  const int bx = blockIdx.x, tid = threadIdx.x;
  if (bx < 512) {
    __shared__ float swmax;
    if (tid < 64) {
      float m = fmaxf(fmaxf(wmaxp[tid], wmaxp[tid + 64]),
                      fmaxf(wmaxp[tid + 128], wmaxp[tid + 192]));
#pragma unroll
      for (int o = 32; o > 0; o >>= 1) m = fmaxf(m, __shfl_down(m, o, 64));
      if (tid == 0) {
        float a = fmaxf(m, 1e-8f);
        swmax = a;
        if (bx == 0) fin[1] = a;
      }
    }
    __syncthreads();
    const float wmax = swmax;
    int t = bx * 256 + tid;
    int c16 = t & 31, k = (t >> 5) & 3, o = t >> 7;
    unsigned words[4];
#pragma unroll
    for (int q = 0; q < 4; ++q) {
      unsigned wd = 0;
#pragma unroll
      for (int j = 0; j < 4; ++j) {
        int c = c16 * 16 + q * 4 + j;
        float v = fminf(fmaxf(w[(size_t)o * 512 + c] / wmax, -1.f), 1.f);
        int wi = (int)rintf(v * 127.0f);
        unsigned wu = (unsigned)(wi + 128);
        unsigned cell = (wu >> (2 * k)) & 3u;
        wd |= (3u * cell + 1u) << (8 * j);
      }
      words[q] = wd;
    }
    *(uint4*)(wgt + ((size_t)(o * 4 + k) * 512 + c16 * 16) / 4) =
        make_uint4(words[0], words[1], words[2], words[3]);
  } else {
    int id = (bx - 512) * 256 + tid;
    int g = id & 3, z = (id >> 2) & 7, n = id >> 5;
    const uint4* a = (const uint4*)(act + (size_t)(n * 8 + z) * 512 + g * 128);
    int xs = 0;
#pragma unroll
    for (int t8 = 0; t8 < 8; ++t8) {
      uint4 v = a[t8];
      xs += __popc(v.x) + __popc(v.y) + __popc(v.z) + __popc(v.w);
    }
    unsigned q0 = (__umul24((unsigned)xs, 51610u) + 524288u) >> 20;   // round(63xs/1280)
    unsigned q3 = (__umul24((unsigned)xs, 361268u) + 524288u) >> 20;  // round(441xs/1280)
    int term = (int)((__umul24(q0, 21u) + (q3 << 6)) << z);
#pragma unroll
    for (int msk = 1; msk <= 16; msk <<= 1) term += __shfl_xor(term, msk, 64);
    if ((tid & 31) == 0) dummy[n] = term;
  }
}

// ---------- k4: main. grid (32 cblk, 196 mblk), 128x128 tile ----------
// B-only LDS (2 x 16 KB double buffer); A per-stage register prefetch.
#define STAGEB(s_, p_) {                                  \
  char* lb = lds + (p_) * 16384 + ldst;                   \
  gload(gB + (s_) * 128 +  0, lb);                        \
  gload(gB + (s_) * 128 + 32, lb + 4096);                 \
  gload(gB + (s_) * 128 + 64, lb + 8192);                 \
  gload(gB + (s_) * 128 + 96, lb + 12288);                \
}

#define APREF(s_, p_) {                                   \
  ar[p_][0] = *(const i32x4*)(gA + (s_) * 128 +  0);      \
  ar[p_][1] = *(const i32x4*)(gA + (s_) * 128 + 32);      \
  ar[p_][2] = *(const i32x4*)(gA + (s_) * 128 + 64);      \
  ar[p_][3] = *(const i32x4*)(gA + (s_) * 128 + 96);      \
}

#define CPASS(pb_, p_, cp0_) {                                        \
  i32x16 c0, c1;                                                      \
  _Pragma("unroll")                                                   \
  for (int e = 0; e < 16; ++e) { c0[e] = 0; c1[e] = 0; }              \
  _Pragma("unroll")                                                   \
  for (int j = 0; j < 4; ++j) {                                       \
    i32x4 b0 = *(const i32x4*)(rB + (pb_) + j * 4096 + (cp0_) * 512); \
    i32x4 b1 = *(const i32x4*)(rB + (pb_) + j * 4096 + (cp0_) * 512 + 512); \
    c0 = __builtin_amdgcn_mfma_i32_32x32x32_i8(ar[p_][j], b0, c0, 0, 0, 0); \
    c1 = __builtin_amdgcn_mfma_i32_32x32x32_i8(ar[p_][j], b1, c1, 0, 0, 0); \
  }                                                                   \
  _Pragma("unroll")                                                   \
  for (int e = 0; e < 16; ++e) {                                      \
    unsigned q0q = (__umul24((unsigned)c0[e], 51610u) + 524288u) >> 20; \
    acc[(cp0_)][e >> 2] += (int)(q0q << shr[e & 3]);                  \
    unsigned q1q = (__umul24((unsigned)c1[e], 51610u) + 524288u) >> 20; \
    acc[(cp0_) + 1][e >> 2] += (int)(q1q << shr[e & 3]);              \
  }                                                                   \
}

#define COMPUTE(pb_, p_) { CPASS(pb_, p_, 0) CPASS(pb_, p_, 2) }

__global__ __launch_bounds__(256, 4) void shortcutq_main_kernel(
    const char* __restrict__ act, const char* __restrict__ wgt,
    const int* __restrict__ dummy, const float* __restrict__ y,
    const float* __restrict__ fin, float* __restrict__ out) {
  __shared__ __align__(16) char lds[32768];
  const int tid = threadIdx.x;
  const int cblk = blockIdx.x;   // 32 (x-fastest: wgt slice hot in L2)
  const int mblk = blockIdx.y;   // 196
  const int lane = tid & 63, wv = tid >> 6;

  const char* gA = act + (size_t)(mblk * 128 + wv * 32 + (lane & 31)) * 512 +
                   (lane >> 5) * 16;
  const char* gB = wgt + (size_t)(cblk * 128 + (tid & 127)) * 512 + (tid >> 7) * 16;
  const int ldst = tid * 16;

  const char* rB = lds + (lane >> 5) * 2048 + (lane & 31) * 16;

  const int shb = 4 * (lane >> 5) + 2 * (lane & 3);
  int shr[4] = {shb, shb + 1, shb + 2, shb + 3};

  i32x4 ar[2][4];
  int acc[4][4];
#pragma unroll
  for (int i = 0; i < 4; ++i)
#pragma unroll
    for (int j = 0; j < 4; ++j) acc[i][j] = 0;

  APREF(0, 0)
  STAGEB(0, 0)
  __syncthreads();
  APREF(1, 1)
  STAGEB(1, 1)
  COMPUTE(0, 0)
  __syncthreads();
  APREF(2, 0)
  STAGEB(2, 0)
  COMPUTE(16384, 1)
  __syncthreads();
  APREF(3, 1)
  STAGEB(3, 1)
  COMPUTE(0, 0)
  __syncthreads();
  COMPUTE(16384, 1)

  // epilogue: sum over k (lane^1, lane^2) and z-half (lane^32)
  const float scale = (float)((128.0 * (3.0 + 1.0 / 3.0)) / 63.0) *
                      (fin[1] / 127.0f) * (fin[0] / 255.0f);
  int sums[4][4];
#pragma unroll
  for (int cp = 0; cp < 4; ++cp)
#pragma unroll
    for (int cc = 0; cc < 4; ++cc) {
      int v = acc[cp][cc];
      v += __shfl_xor(v, 1, 64);
      v += __shfl_xor(v, 2, 64);
      v += __shfl_xor(v, 32, 64);
      sums[cp][cc] = v;
    }
  if ((lane & 3) == 0 && lane < 32) {
    const int ol = lane >> 2;   // 0..7
#pragma unroll
    for (int cc = 0; cc < 4; ++cc) {
      int n = mblk * 16 + wv * 4 + cc;
      int d = dummy[n];
      int b = n / 196, hw = n - b * 196;
#pragma unroll
      for (int cp = 0; cp < 4; ++cp) {
        int o = cblk * 32 + cp * 8 + ol;
        size_t idx = ((size_t)(b * 1024 + o)) * 196 + hw;
        out[idx] = (float)(sums[cp][cc] - d) * scale + y[idx];
      }
    }
  }
}

extern "C" void kernel_launch(void* const* d_in, const int* in_sizes, int n_in,
                              void* d_out, int out_size, void* d_ws, size_t ws_size,
                              hipStream_t stream) {
  const float* x     = (const float*)d_in[0];
  const float* y     = (const float*)d_in[1];
  const float* gamma = (const float*)d_in[2];
  const float* beta  = (const float*)d_in[3];
  const float* mean  = (const float*)d_in[4];
  const float* var   = (const float*)d_in[5];
  const float* w     = (const float*)d_in[6];
  float* out = (float*)d_out;

  char* wsb = (char*)d_ws;
  float* fin    = (float*)(wsb + FIN_OFF);
  float* amaxp  = (float*)(wsb + AMAXP_OFF);
  float* wmaxp  = (float*)(wsb + WMAXP_OFF);
  float* chs    = (float*)(wsb + CHS_OFF);
  int*   dum    = (int*)(wsb + DUM_OFF);
  char*  actb   = wsb + ACT_OFF;
  char*  wgtb   = wsb + WGT_OFF;

  hipLaunchKernelGGL(prep1_kernel, dim3(1154), dim3(256), 0, stream,
                     x, w, gamma, beta, mean, var, amaxp, wmaxp, chs);
  hipLaunchKernelGGL(pack_x_kernel, dim3(448), dim3(256), 0, stream,
                     x, mean, beta, chs, amaxp, (unsigned*)actb, fin);
  hipLaunchKernelGGL(pack_wd_kernel, dim3(904), dim3(256), 0, stream,
                     w, wmaxp, (const unsigned char*)actb, (unsigned*)wgtb, dum, fin);
  hipLaunchKernelGGL(shortcutq_main_kernel, dim3(32, 196), dim3(256), 0, stream,
                     actb, wgtb, dum, y, fin, out);
}